// Round 4
// baseline (189.989 us; speedup 1.0000x reference)
//
#include <hip/hip_runtime.h>

// LogSumExpPooling2D: x (8,256,256,64) f32 NHWC ->
// out (1,128,128,64): (1/100)*logsumexp(100*x) over 2x2 stride-2 window AND batch.
// Memory-bound: 134 MB read + 4 MB write, ~22 us HBM floor @ 6.3-6.9 TB/s.
//
// R4: occupancy/MLP probe. 2-way batch split: each wave does 4 of 8 batches
// for its 8 pixel-columns (contiguous 1-KiB wave loads as R3), halves combine
// via padded LDS. Grid 2048 blocks -> 2x resident waves, 2x loads in flight.

constexpr float SCALE = 100.0f;
constexpr float INV_SCALE = 0.01f;

__device__ inline void pair_merge(float& m, float& s, float m2, float s2) {
    const float mn = fmaxf(m, m2);
    s = s * __expf((m - mn) * SCALE) + s2 * __expf((m2 - mn) * SCALE);
    m = mn;
}

__device__ inline void chunk_merge(const float4& v0, const float4& v1,
                                   float m[4], float s[4]) {
    const float e0[4] = {v0.x, v0.y, v0.z, v0.w};
    const float e1[4] = {v1.x, v1.y, v1.z, v1.w};
#pragma unroll
    for (int j = 0; j < 4; ++j) {
        const float cm = fmaxf(e0[j], e1[j]);
        const float cs = __expf((e0[j] - cm) * SCALE) + __expf((e1[j] - cm) * SCALE);
        pair_merge(m[j], s[j], cm, cs);
    }
}

__global__ __launch_bounds__(256) void lse_pool_kernel(const float* __restrict__ x,
                                                       float* __restrict__ out) {
    const int t    = threadIdx.x;
    const int l    = t & 63;         // lane
    const int w    = t >> 6;         // wave in block: 0..3
    const int g    = w & 1;          // column-group within block
    const int half = w >> 1;         // batch half: n in [4*half, 4*half+4)
    const int ho   = blockIdx.x >> 4;                      // output row 0..127
    const int p0   = ((blockIdx.x & 15) << 4) + (g << 3);  // input pixel base

    const size_t NS = (size_t)256 * 256 * 64;  // batch stride (floats)
    const size_t HS = (size_t)256 * 64;        // row stride (floats)
    // Wave's 64 lanes form one contiguous 1 KiB per load; lane l covers
    // pixel p0+(l>>4) (A) / p0+4+(l>>4) (B), channels 4*(l&15)..+3.
    const float* base = x + (((size_t)(2 * ho) * 256) + (size_t)p0) * 64
                          + (size_t)(half * 4) * NS + (size_t)(l * 4);

    float mA[4], sA[4], mB[4], sB[4];
#pragma unroll
    for (int j = 0; j < 4; ++j) { mA[j] = -1e30f; sA[j] = 0.f; mB[j] = -1e30f; sB[j] = 0.f; }

#pragma unroll 2
    for (int n = 0; n < 4; ++n) {
        const float* pn = base + (size_t)n * NS;
        const float4 a0 = *reinterpret_cast<const float4*>(pn);            // dh=0 cols 0-3
        const float4 b0 = *reinterpret_cast<const float4*>(pn + 256);      // dh=0 cols 4-7
        const float4 a1 = *reinterpret_cast<const float4*>(pn + HS);       // dh=1 cols 0-3
        const float4 b1 = *reinterpret_cast<const float4*>(pn + HS + 256); // dh=1 cols 4-7
        chunk_merge(a0, a1, mA, sA);
        chunk_merge(b0, b1, mB, sB);
    }

    // intra-wave dw-pair merge: lanes l and l^16 hold adjacent pixel columns
#pragma unroll
    for (int j = 0; j < 4; ++j) {
        pair_merge(mA[j], sA[j], __shfl_xor(mA[j], 16), __shfl_xor(sA[j], 16));
        pair_merge(mB[j], sB[j], __shfl_xor(mB[j], 16), __shfl_xor(sB[j], 16));
    }

    // cross-half combine via LDS (pad 16->17 words: conflict-free)
    __shared__ float lds[2][64][17];
    if (half == 1) {
#pragma unroll
        for (int j = 0; j < 4; ++j) {
            lds[g][l][j]      = mA[j];
            lds[g][l][4 + j]  = sA[j];
            lds[g][l][8 + j]  = mB[j];
            lds[g][l][12 + j] = sB[j];
        }
    }
    __syncthreads();

    if (half == 0 && (l & 16) == 0) {
#pragma unroll
        for (int j = 0; j < 4; ++j) {
            pair_merge(mA[j], sA[j], lds[g][l][j],     lds[g][l][4 + j]);
            pair_merge(mB[j], sB[j], lds[g][l][8 + j], lds[g][l][12 + j]);
        }
        float4 rA, rB;
        rA.x = mA[0] + __logf(sA[0]) * INV_SCALE;
        rA.y = mA[1] + __logf(sA[1]) * INV_SCALE;
        rA.z = mA[2] + __logf(sA[2]) * INV_SCALE;
        rA.w = mA[3] + __logf(sA[3]) * INV_SCALE;
        rB.x = mB[0] + __logf(sB[0]) * INV_SCALE;
        rB.y = mB[1] + __logf(sB[1]) * INV_SCALE;
        rB.z = mB[2] + __logf(sB[2]) * INV_SCALE;
        rB.w = mB[3] + __logf(sB[3]) * INV_SCALE;

        const int c  = (l & 15) << 2;
        const int wo = (p0 >> 1) + (l >> 5);   // A's output pixel; B is +2
        const size_t o = ((size_t)ho * 128 + (size_t)wo) * 64 + (size_t)c;
        *reinterpret_cast<float4*>(out + o)       = rA;
        *reinterpret_cast<float4*>(out + o + 128) = rB;
    }
}

extern "C" void kernel_launch(void* const* d_in, const int* in_sizes, int n_in,
                              void* d_out, int out_size, void* d_ws, size_t ws_size,
                              hipStream_t stream) {
    const float* x = (const float*)d_in[0];
    float* out = (float*)d_out;
    // 128 rows x 16 column-blocks = 2048 blocks of 256 (8192 waves total)
    lse_pool_kernel<<<2048, 256, 0, stream>>>(x, out);
}